// Round 1
// baseline (411.015 us; speedup 1.0000x reference)
//
#include <hip/hip_runtime.h>

typedef float v4 __attribute__((ext_vector_type(4)));

__device__ __forceinline__ float leaky(float x) { return x >= 0.f ? x : 0.2f * x; }
__device__ __forceinline__ float elu(float x) { return x > 0.f ? x : expm1f(x); }

// ---------------- CSR build (dst-major) ----------------
__global__ void k_deg(const int* __restrict__ ei, int* __restrict__ deg, int nE, int eT) {
  int e = blockIdx.x * blockDim.x + threadIdx.x;
  if (e >= eT) return;
  int d = (e < nE) ? ei[nE + e] : (e - nE);   // self-loops appended after real edges
  atomicAdd(&deg[d], 1);
}

__global__ void k_scan(const int* __restrict__ deg, int* __restrict__ rowptr,
                       int* __restrict__ cursor, int nN, int eT) {
  __shared__ int sd[1024];
  int t = threadIdx.x;
  int chunk = (nN + 1023) >> 10;
  int beg = t * chunk;
  int end = beg + chunk; if (end > nN) end = nN;
  int s = 0;
  for (int i = beg; i < end; ++i) s += deg[i];
  sd[t] = s;
  __syncthreads();
  for (int off = 1; off < 1024; off <<= 1) {
    int v = (t >= off) ? sd[t - off] : 0;
    __syncthreads();
    sd[t] += v;
    __syncthreads();
  }
  int run = sd[t] - s;  // exclusive prefix of this thread's chunk
  for (int i = beg; i < end; ++i) { rowptr[i] = run; cursor[i] = run; run += deg[i]; }
  if (t == 0) rowptr[nN] = eT;
}

__global__ void k_scatter(const int* __restrict__ ei, int* __restrict__ cursor,
                          int* __restrict__ srt, int nE, int eT) {
  int e = blockIdx.x * blockDim.x + threadIdx.x;
  if (e >= eT) return;
  int s, d;
  if (e < nE) { s = ei[e]; d = ei[nE + e]; } else { s = d = e - nE; }
  int pos = atomicAdd(&cursor[d], 1);
  srt[pos] = s;
}

// ---------------- GEMM1: h1[n,256] = emb[nidx[n],128] @ W1[128,256] ----------------
__global__ __launch_bounds__(512) void k_gemm1(
    const int* __restrict__ nidx, const float* __restrict__ emb,
    const float* __restrict__ W1, float* __restrict__ h1, int nN) {
  __shared__ __align__(16) float Ws[32 * 256];   // 32 d-rows of W1
  __shared__ __align__(16) float xs[32 * 128];   // 32 gathered x rows
  int t = threadIdx.x;
  int base = blockIdx.x * 32;
  for (int i = t; i < 32 * 128; i += 512) {
    int j = i >> 7, d = i & 127;
    int n = base + j;
    if (n < nN) xs[i] = emb[(size_t)nidx[n] * 128 + d];
  }
  int w = t >> 6, lane = t & 63;
  float acc[4][4];
  for (int a = 0; a < 4; ++a) for (int b = 0; b < 4; ++b) acc[a][b] = 0.f;
  for (int ck = 0; ck < 4; ++ck) {
    __syncthreads();
    for (int i = t; i < 32 * 256; i += 512) Ws[i] = W1[ck * 8192 + i];
    __syncthreads();
    int xoff = ck * 32;
    for (int d4 = 0; d4 < 32; d4 += 4) {
      v4 xv[4];
      for (int nn = 0; nn < 4; ++nn)
        xv[nn] = *(const v4*)&xs[(w * 4 + nn) * 128 + xoff + d4];
      for (int dd = 0; dd < 4; ++dd) {
        v4 wv = *(const v4*)&Ws[(d4 + dd) * 256 + lane * 4];
        for (int nn = 0; nn < 4; ++nn) {
          float xd = xv[nn][dd];
          acc[nn][0] += xd * wv[0];
          acc[nn][1] += xd * wv[1];
          acc[nn][2] += xd * wv[2];
          acc[nn][3] += xd * wv[3];
        }
      }
    }
  }
  for (int nn = 0; nn < 4; ++nn) {
    int n = base + w * 4 + nn;
    if (n < nN) {
      v4 o; o[0] = acc[nn][0]; o[1] = acc[nn][1]; o[2] = acc[nn][2]; o[3] = acc[nn][3];
      *(v4*)&h1[(size_t)n * 256 + lane * 4] = o;
    }
  }
}

// ---------------- per-node attention coefficients, layer 1 ----------------
__global__ void k_alpha1(const float* __restrict__ h1, const float* __restrict__ asv,
                         const float* __restrict__ adv, float* __restrict__ as1,
                         float* __restrict__ ad1, int nN) {
  int t = threadIdx.x;
  int n = blockIdx.x * 4 + (t >> 6);
  int c = t & 63;
  if (n >= nN) return;
  for (int h = 0; h < 4; ++h) {
    float hv = h1[(size_t)n * 256 + h * 64 + c];
    float ps = hv * asv[h * 64 + c];
    float pd = hv * adv[h * 64 + c];
    for (int off = 32; off; off >>= 1) {
      ps += __shfl_xor(ps, off);
      pd += __shfl_xor(pd, off);
    }
    if (c == 0) { as1[n * 4 + h] = ps; ad1[n * 4 + h] = pd; }
  }
}

// ---------------- layer-1 softmax + aggregate + bias + ELU (one pass) ----------------
__global__ void k_agg1(const float* __restrict__ h1, const float* __restrict__ as1,
                       const float* __restrict__ ad1, const float* __restrict__ b1,
                       const int* __restrict__ rowptr, const int* __restrict__ srt,
                       float* __restrict__ x2, int nN) {
  int n = blockIdx.x;
  int t = threadIdx.x;          // t = h*64 + c
  int h = t >> 6;
  float adn = ad1[n * 4 + h];
  int s0 = rowptr[n], s1 = rowptr[n + 1];
  float acc = 0.f, den = 0.f;
  for (int i = s0; i < s1; ++i) {
    int s = srt[i];
    float wgt = __expf(leaky(as1[s * 4 + h] + adn));
    den += wgt;
    acc += wgt * h1[(size_t)s * 256 + t];
  }
  float o = acc / den + b1[t];
  x2[(size_t)n * 256 + t] = elu(o);
}

// ---------------- GEMM2: h2[n,64] = x2[n,256] @ W2[256,64] ----------------
__global__ __launch_bounds__(512) void k_gemm2(
    const float* __restrict__ x2, const float* __restrict__ W2,
    float* __restrict__ h2, int nN) {
  __shared__ __align__(16) float Wt[64 * 132];   // W2^T chunk, pad 132 (16B-aligned, bank-spread)
  __shared__ __align__(16) float xs[32 * 128];
  int t = threadIdx.x;
  int base = blockIdx.x * 32;
  int w = t >> 6, lane = t & 63;
  float acc[4] = {0.f, 0.f, 0.f, 0.f};
  for (int ck = 0; ck < 2; ++ck) {
    __syncthreads();
    for (int i = t; i < 128 * 64; i += 512) {
      int d = i >> 6, c = i & 63;
      Wt[c * 132 + d] = W2[ck * 8192 + i];       // coalesced global read
    }
    for (int i = t; i < 32 * 128; i += 512) {
      int j = i >> 7, d = i & 127;
      int n = base + j;
      if (n < nN) xs[i] = x2[(size_t)n * 256 + ck * 128 + d];
    }
    __syncthreads();
    for (int d4 = 0; d4 < 128; d4 += 4) {
      v4 wv = *(const v4*)&Wt[lane * 132 + d4];
      for (int nn = 0; nn < 4; ++nn) {
        v4 xv = *(const v4*)&xs[(w * 4 + nn) * 128 + d4];
        acc[nn] += xv[0] * wv[0] + xv[1] * wv[1] + xv[2] * wv[2] + xv[3] * wv[3];
      }
    }
  }
  for (int nn = 0; nn < 4; ++nn) {
    int n = base + w * 4 + nn;
    if (n < nN) h2[(size_t)n * 64 + lane] = acc[nn];
  }
}

// ---------------- per-node attention coefficients, layer 2 ----------------
__global__ void k_alpha2(const float* __restrict__ h2, const float* __restrict__ asv,
                         const float* __restrict__ adv, float* __restrict__ as2,
                         float* __restrict__ ad2, int nN) {
  int t = threadIdx.x;
  int n = blockIdx.x * 4 + (t >> 6);
  int c = t & 63;
  if (n >= nN) return;
  float hv = h2[(size_t)n * 64 + c];
  float ps = hv * asv[c];
  float pd = hv * adv[c];
  for (int off = 32; off; off >>= 1) { ps += __shfl_xor(ps, off); pd += __shfl_xor(pd, off); }
  if (c == 0) { as2[n] = ps; ad2[n] = pd; }
}

// ---------------- layer-2 softmax + aggregate + bias + ELU ----------------
__global__ void k_agg2(const float* __restrict__ h2, const float* __restrict__ as2,
                       const float* __restrict__ ad2, const float* __restrict__ b2,
                       const int* __restrict__ rowptr, const int* __restrict__ srt,
                       float* __restrict__ x3, int nN) {
  int t = threadIdx.x;
  int n = blockIdx.x * 4 + (t >> 6);
  int c = t & 63;
  if (n >= nN) return;
  float adn = ad2[n];
  int s0 = rowptr[n], s1 = rowptr[n + 1];
  float acc = 0.f, den = 0.f;
  for (int i = s0; i < s1; ++i) {
    int s = srt[i];
    float wgt = __expf(leaky(as2[s] + adn));
    den += wgt;
    acc += wgt * h2[(size_t)s * 64 + c];
  }
  x3[(size_t)n * 64 + c] = elu(acc / den + b2[c]);
}

// ---------------- gate MLP: gbuf[n] = exp(relu(x3@gW1+gb1)@gW2+gb2) ----------------
__global__ void k_gate(const float* __restrict__ x3, const float* __restrict__ gW1,
                       const float* __restrict__ gb1, const float* __restrict__ gW2,
                       const float* __restrict__ gb2, float* __restrict__ gbuf, int nN) {
  __shared__ float gw[64 * 64];
  __shared__ float xr[4][64];
  int t = threadIdx.x;
  int w = t >> 6, c = t & 63;
  int n = blockIdx.x * 4 + w;
  for (int i = t; i < 4096; i += 256) gw[i] = gW1[i];
  xr[w][c] = (n < nN) ? x3[(size_t)n * 64 + c] : 0.f;
  __syncthreads();
  float hid = 0.f;
  for (int d = 0; d < 64; ++d) hid += xr[w][d] * gw[d * 64 + c];
  hid += gb1[c];
  hid = fmaxf(hid, 0.f);
  float p = hid * gW2[c];
  for (int off = 32; off; off >>= 1) p += __shfl_xor(p, off);
  if (c == 0 && n < nN) gbuf[n] = __expf(p + gb2[0]);
}

// ---------------- pooling partials (256 blocks) ----------------
__global__ void k_pool(const float* __restrict__ x3, const float* __restrict__ gbuf,
                       float* __restrict__ pnum, float* __restrict__ pden, int nN) {
  __shared__ float snum[4][64];
  __shared__ float sden[4];
  int t = threadIdx.x;
  int g = t >> 6, c = t & 63;
  float numl = 0.f, denl = 0.f;
  for (int n = blockIdx.x * 4 + g; n < nN; n += 1024) {
    float e = gbuf[n];
    numl += e * x3[(size_t)n * 64 + c];
    denl += e;
  }
  snum[g][c] = numl;
  if (c == 0) sden[g] = denl;
  __syncthreads();
  if (t < 64)
    pnum[blockIdx.x * 64 + t] = snum[0][t] + snum[1][t] + snum[2][t] + snum[3][t];
  if (t == 0) pden[blockIdx.x] = sden[0] + sden[1] + sden[2] + sden[3];
}

__global__ void k_final(const float* __restrict__ pnum, const float* __restrict__ pden,
                        float* __restrict__ out) {
  int t = threadIdx.x;  // 64 threads
  float s = 0.f, dn = 0.f;
  for (int b = 0; b < 256; ++b) { s += pnum[b * 64 + t]; dn += pden[b]; }
  out[t] = s / dn;
}

extern "C" void kernel_launch(void* const* d_in, const int* in_sizes, int n_in,
                              void* d_out, int out_size, void* d_ws, size_t ws_size,
                              hipStream_t stream) {
  const int*   nidx = (const int*)d_in[0];
  const int*   ei   = (const int*)d_in[1];
  const float* emb  = (const float*)d_in[2];
  const float* W1   = (const float*)d_in[3];
  const float* as1v = (const float*)d_in[4];
  const float* ad1v = (const float*)d_in[5];
  const float* b1   = (const float*)d_in[6];
  const float* W2   = (const float*)d_in[7];
  const float* as2v = (const float*)d_in[8];
  const float* ad2v = (const float*)d_in[9];
  const float* b2   = (const float*)d_in[10];
  const float* gW1  = (const float*)d_in[11];
  const float* gb1  = (const float*)d_in[12];
  const float* gW2  = (const float*)d_in[13];
  const float* gb2  = (const float*)d_in[14];
  float* out = (float*)d_out;

  const int nN = in_sizes[0];
  const int nE = in_sizes[1] / 2;
  const int eT = nE + nN;

  float* f = (float*)d_ws;
  size_t off = 0;
  float* h1   = f + off; off += (size_t)nN * 256;  // later reused: h2 at h1, x3 at h1+nN*128
  float* x2   = f + off; off += (size_t)nN * 256;
  float* as1  = f + off; off += (size_t)nN * 4;
  float* ad1  = f + off; off += (size_t)nN * 4;
  float* as2  = f + off; off += nN;
  float* ad2  = f + off; off += nN;
  float* gbuf = f + off; off += nN;
  float* pnum = f + off; off += 256 * 64;
  float* pden = f + off; off += 256;
  int* deg    = (int*)(f + off); off += nN;
  int* rowptr = (int*)(f + off); off += nN + 1;
  int* cursor = (int*)(f + off); off += nN;
  int* srt    = (int*)(f + off); off += eT;

  float* h2 = h1;                        // h1 dead after k_agg1
  float* x3 = h1 + (size_t)nN * 128;     // disjoint from h2 (nN*64)

  hipMemsetAsync(deg, 0, (size_t)nN * sizeof(int), stream);

  int eb = (eT + 255) / 256;
  k_deg    <<<eb, 256, 0, stream>>>(ei, deg, nE, eT);
  k_scan   <<<1, 1024, 0, stream>>>(deg, rowptr, cursor, nN, eT);
  k_scatter<<<eb, 256, 0, stream>>>(ei, cursor, srt, nE, eT);

  k_gemm1 <<<(nN + 31) / 32, 512, 0, stream>>>(nidx, emb, W1, h1, nN);
  k_alpha1<<<(nN + 3) / 4, 256, 0, stream>>>(h1, as1v, ad1v, as1, ad1, nN);
  k_agg1  <<<nN, 256, 0, stream>>>(h1, as1, ad1, b1, rowptr, srt, x2, nN);

  k_gemm2 <<<(nN + 31) / 32, 512, 0, stream>>>(x2, W2, h2, nN);
  k_alpha2<<<(nN + 3) / 4, 256, 0, stream>>>(h2, as2v, ad2v, as2, ad2, nN);
  k_agg2  <<<(nN + 3) / 4, 256, 0, stream>>>(h2, as2, ad2, b2, rowptr, srt, x3, nN);

  k_gate <<<(nN + 3) / 4, 256, 0, stream>>>(x3, gW1, gb1, gW2, gb2, gbuf, nN);
  k_pool <<<256, 256, 0, stream>>>(x3, gbuf, pnum, pden, nN);
  k_final<<<1, 64, 0, stream>>>(pnum, pden, out);
}

// Round 2
// 336.066 us; speedup vs baseline: 1.2230x; 1.2230x over previous
//
#include <hip/hip_runtime.h>

typedef float v4 __attribute__((ext_vector_type(4)));

__device__ __forceinline__ float leaky(float x) { return x >= 0.f ? x : 0.2f * x; }
__device__ __forceinline__ float elu(float x) { return x > 0.f ? x : expm1f(x); }

// ---------------- CSR build (dst-major) ----------------
__global__ void k_deg(const int* __restrict__ ei, int* __restrict__ deg, int nE, int eT) {
  int e = blockIdx.x * blockDim.x + threadIdx.x;
  if (e >= eT) return;
  int d = (e < nE) ? ei[nE + e] : (e - nE);   // self-loops appended after real edges
  atomicAdd(&deg[d], 1);
}

__global__ void k_scan(const int* __restrict__ deg, int* __restrict__ rowptr,
                       int* __restrict__ cursor, int nN, int eT) {
  __shared__ int sd[1024];
  int t = threadIdx.x;
  int chunk = (nN + 1023) >> 10;
  int beg = t * chunk;
  int end = beg + chunk; if (end > nN) end = nN;
  int s = 0;
  for (int i = beg; i < end; ++i) s += deg[i];
  sd[t] = s;
  __syncthreads();
  for (int off = 1; off < 1024; off <<= 1) {
    int v = (t >= off) ? sd[t - off] : 0;
    __syncthreads();
    sd[t] += v;
    __syncthreads();
  }
  int run = sd[t] - s;  // exclusive prefix of this thread's chunk
  for (int i = beg; i < end; ++i) { rowptr[i] = run; cursor[i] = run; run += deg[i]; }
  if (t == 0) rowptr[nN] = eT;
}

__global__ void k_scatter(const int* __restrict__ ei, int* __restrict__ cursor,
                          int* __restrict__ srt, int nE, int eT) {
  int e = blockIdx.x * blockDim.x + threadIdx.x;
  if (e >= eT) return;
  int s, d;
  if (e < nE) { s = ei[e]; d = ei[nE + e]; } else { s = d = e - nE; }
  int pos = atomicAdd(&cursor[d], 1);
  srt[pos] = s;
}

// ---- GEMM1: h1[n,256] = emb[nidx[n],128] @ W1[128,256]; epilogue computes as1/ad1 ----
__global__ __launch_bounds__(512) void k_gemm1(
    const int* __restrict__ nidx, const float* __restrict__ emb,
    const float* __restrict__ W1, const float* __restrict__ asv,
    const float* __restrict__ adv, float* __restrict__ h1,
    float* __restrict__ as1, float* __restrict__ ad1, int nN) {
  __shared__ __align__(16) float Ws[32 * 256];   // 32 d-rows of W1
  __shared__ __align__(16) float xs[32 * 128];   // 32 gathered x rows
  int t = threadIdx.x;
  int base = blockIdx.x * 32;
  for (int i = t; i < 32 * 128; i += 512) {
    int j = i >> 7, d = i & 127;
    int n = base + j;
    if (n < nN) xs[i] = emb[(size_t)nidx[n] * 128 + d];
  }
  int w = t >> 6, lane = t & 63;
  float acc[4][4];
  for (int a = 0; a < 4; ++a) for (int b = 0; b < 4; ++b) acc[a][b] = 0.f;
  for (int ck = 0; ck < 4; ++ck) {
    __syncthreads();
    for (int i = t; i < 32 * 256; i += 512) Ws[i] = W1[ck * 8192 + i];
    __syncthreads();
    int xoff = ck * 32;
    for (int d4 = 0; d4 < 32; d4 += 4) {
      v4 xv[4];
      for (int nn = 0; nn < 4; ++nn)
        xv[nn] = *(const v4*)&xs[(w * 4 + nn) * 128 + xoff + d4];
      for (int dd = 0; dd < 4; ++dd) {
        v4 wv = *(const v4*)&Ws[(d4 + dd) * 256 + lane * 4];
        for (int nn = 0; nn < 4; ++nn) {
          float xd = xv[nn][dd];
          acc[nn][0] += xd * wv[0];
          acc[nn][1] += xd * wv[1];
          acc[nn][2] += xd * wv[2];
          acc[nn][3] += xd * wv[3];
        }
      }
    }
  }
  v4 asl = *(const v4*)&asv[lane * 4];
  v4 adl = *(const v4*)&adv[lane * 4];
  for (int nn = 0; nn < 4; ++nn) {
    int n = base + w * 4 + nn;
    if (n < nN) {
      v4 o; o[0] = acc[nn][0]; o[1] = acc[nn][1]; o[2] = acc[nn][2]; o[3] = acc[nn][3];
      *(v4*)&h1[(size_t)n * 256 + lane * 4] = o;
      float ps = o[0]*asl[0] + o[1]*asl[1] + o[2]*asl[2] + o[3]*asl[3];
      float pd = o[0]*adl[0] + o[1]*adl[1] + o[2]*adl[2] + o[3]*adl[3];
      for (int off = 8; off; off >>= 1) {
        ps += __shfl_xor(ps, off);
        pd += __shfl_xor(pd, off);
      }
      if ((lane & 15) == 0) {
        as1[(size_t)n * 4 + (lane >> 4)] = ps;
        ad1[(size_t)n * 4 + (lane >> 4)] = pd;
      }
    }
  }
}

// ---- layer-1 softmax + aggregate + bias + ELU: one wave per node, v4 channels ----
__global__ __launch_bounds__(256) void k_agg1(
    const float* __restrict__ h1, const float* __restrict__ as1,
    const float* __restrict__ ad1, const float* __restrict__ b1,
    const int* __restrict__ rowptr, const int* __restrict__ srt,
    float* __restrict__ x2, int nN) {
  __shared__ int   ss[4][64];
  __shared__ float sw[4][256];
  __shared__ int   mx;
  int t = threadIdx.x;
  int wv = t >> 6, lane = t & 63;
  int n = blockIdx.x * 4 + wv;
  bool valid = n < nN;
  int ms0 = 0, ms1 = 0;
  v4 adn = (v4)(0.f);
  if (valid) {
    ms0 = rowptr[n]; ms1 = rowptr[n + 1];
    adn = *(const v4*)&ad1[(size_t)n * 4];
  }
  if (t == 0) mx = 0;
  __syncthreads();
  int myc = valid ? (ms1 - ms0 + 63) >> 6 : 0;
  if (lane == 0) atomicMax(&mx, myc);
  __syncthreads();
  int nchunk = mx;
  int h = lane >> 4;
  v4 acc = (v4)(0.f);
  float den = 0.f;
  for (int c = 0; c < nchunk; ++c) {
    int base = ms0 + c * 64;
    int m = ms1 - base; if (m > 64) m = 64;
    if (lane < m) {
      int s = srt[base + lane];
      ss[wv][lane] = s;
      v4 a = *(const v4*)&as1[(size_t)s * 4];
      sw[wv][lane * 4 + 0] = __expf(leaky(a[0] + adn[0]));
      sw[wv][lane * 4 + 1] = __expf(leaky(a[1] + adn[1]));
      sw[wv][lane * 4 + 2] = __expf(leaky(a[2] + adn[2]));
      sw[wv][lane * 4 + 3] = __expf(leaky(a[3] + adn[3]));
    }
    __syncthreads();
    #pragma unroll 4
    for (int j = 0; j < m; ++j) {
      int s = ss[wv][j];
      float wj = sw[wv][j * 4 + h];
      v4 hv = *(const v4*)&h1[(size_t)s * 256 + lane * 4];
      acc[0] += wj * hv[0];
      acc[1] += wj * hv[1];
      acc[2] += wj * hv[2];
      acc[3] += wj * hv[3];
      den += wj;
    }
    __syncthreads();
  }
  if (valid) {
    v4 bb = *(const v4*)&b1[lane * 4];
    float inv = 1.f / den;
    v4 o;
    o[0] = elu(acc[0] * inv + bb[0]);
    o[1] = elu(acc[1] * inv + bb[1]);
    o[2] = elu(acc[2] * inv + bb[2]);
    o[3] = elu(acc[3] * inv + bb[3]);
    *(v4*)&x2[(size_t)n * 256 + lane * 4] = o;
  }
}

// ---- GEMM2: h2[n,64] = x2[n,256] @ W2[256,64]; epilogue computes as2/ad2 ----
__global__ __launch_bounds__(512) void k_gemm2(
    const float* __restrict__ x2, const float* __restrict__ W2,
    const float* __restrict__ asv, const float* __restrict__ adv,
    float* __restrict__ h2, float* __restrict__ as2, float* __restrict__ ad2, int nN) {
  __shared__ __align__(16) float Wt[64 * 132];   // W2^T chunk, pad 132
  __shared__ __align__(16) float xs[32 * 128];
  int t = threadIdx.x;
  int base = blockIdx.x * 32;
  int w = t >> 6, lane = t & 63;
  float acc[4] = {0.f, 0.f, 0.f, 0.f};
  for (int ck = 0; ck < 2; ++ck) {
    __syncthreads();
    for (int i = t; i < 128 * 64; i += 512) {
      int d = i >> 6, c = i & 63;
      Wt[c * 132 + d] = W2[ck * 8192 + i];       // coalesced global read
    }
    for (int i = t; i < 32 * 128; i += 512) {
      int j = i >> 7, d = i & 127;
      int n = base + j;
      if (n < nN) xs[i] = x2[(size_t)n * 256 + ck * 128 + d];
    }
    __syncthreads();
    for (int d4 = 0; d4 < 128; d4 += 4) {
      v4 wv = *(const v4*)&Wt[lane * 132 + d4];
      for (int nn = 0; nn < 4; ++nn) {
        v4 xv = *(const v4*)&xs[(w * 4 + nn) * 128 + d4];
        acc[nn] += xv[0] * wv[0] + xv[1] * wv[1] + xv[2] * wv[2] + xv[3] * wv[3];
      }
    }
  }
  float asl = asv[lane], adl = adv[lane];
  for (int nn = 0; nn < 4; ++nn) {
    int n = base + w * 4 + nn;
    if (n < nN) {
      h2[(size_t)n * 64 + lane] = acc[nn];
      float ps = acc[nn] * asl;
      float pd = acc[nn] * adl;
      for (int off = 32; off; off >>= 1) {
        ps += __shfl_xor(ps, off);
        pd += __shfl_xor(pd, off);
      }
      if (lane == 0) { as2[n] = ps; ad2[n] = pd; }
    }
  }
}

// ---- layer-2 softmax + aggregate + bias + ELU: one wave per node ----
__global__ __launch_bounds__(256) void k_agg2(
    const float* __restrict__ h2, const float* __restrict__ as2,
    const float* __restrict__ ad2, const float* __restrict__ b2,
    const int* __restrict__ rowptr, const int* __restrict__ srt,
    float* __restrict__ x3, int nN) {
  __shared__ int   ss[4][64];
  __shared__ float sw[4][64];
  __shared__ int   mx;
  int t = threadIdx.x;
  int wv = t >> 6, lane = t & 63;
  int n = blockIdx.x * 4 + wv;
  bool valid = n < nN;
  int ms0 = 0, ms1 = 0;
  float adn = 0.f;
  if (valid) { ms0 = rowptr[n]; ms1 = rowptr[n + 1]; adn = ad2[n]; }
  if (t == 0) mx = 0;
  __syncthreads();
  int myc = valid ? (ms1 - ms0 + 63) >> 6 : 0;
  if (lane == 0) atomicMax(&mx, myc);
  __syncthreads();
  int nchunk = mx;
  float acc = 0.f, den = 0.f;
  for (int c = 0; c < nchunk; ++c) {
    int base = ms0 + c * 64;
    int m = ms1 - base; if (m > 64) m = 64;
    if (lane < m) {
      int s = srt[base + lane];
      ss[wv][lane] = s;
      sw[wv][lane] = __expf(leaky(as2[s] + adn));
    }
    __syncthreads();
    #pragma unroll 4
    for (int j = 0; j < m; ++j) {
      int s = ss[wv][j];
      float wj = sw[wv][j];
      acc += wj * h2[(size_t)s * 64 + lane];
      den += wj;
    }
    __syncthreads();
  }
  if (valid) x3[(size_t)n * 64 + lane] = elu(acc / den + b2[lane]);
}

// ---- fused gate MLP + pooling partials (exactly 256 blocks x 512 threads) ----
__global__ __launch_bounds__(512) void k_gatepool(
    const float* __restrict__ x3, const float* __restrict__ gW1,
    const float* __restrict__ gb1, const float* __restrict__ gW2,
    const float* __restrict__ gb2, float* __restrict__ pnum,
    float* __restrict__ pden, int nN) {
  __shared__ __align__(16) float gwT[64 * 68];   // gW1^T, padded (4-float aligned)
  __shared__ float xr[8][64];
  __shared__ float snum[8][64];
  __shared__ float sden[8];
  int t = threadIdx.x;
  int wv = t >> 6, lane = t & 63;
  for (int i = t; i < 4096; i += 512) {
    int d = i >> 6, c = i & 63;
    gwT[c * 68 + d] = gW1[i];
  }
  float gb1l = gb1[lane];
  float gw2l = gW2[lane];
  float gb2s = gb2[0];
  __syncthreads();
  float num = 0.f, den = 0.f;
  int nIt = (nN + 2047) >> 11;
  int off0 = blockIdx.x * 8 + wv;
  for (int it = 0; it < nIt; ++it) {
    int n = off0 + it * 2048;
    bool v = n < nN;
    float xv = v ? x3[(size_t)n * 64 + lane] : 0.f;
    xr[wv][lane] = xv;
    __syncthreads();
    float hid = gb1l;
    for (int d4 = 0; d4 < 64; d4 += 4) {
      v4 xs4 = *(const v4*)&xr[wv][d4];
      v4 gv  = *(const v4*)&gwT[lane * 68 + d4];
      hid += xs4[0] * gv[0] + xs4[1] * gv[1] + xs4[2] * gv[2] + xs4[3] * gv[3];
    }
    hid = fmaxf(hid, 0.f);
    float p = hid * gw2l;
    for (int o = 32; o; o >>= 1) p += __shfl_xor(p, o);
    float g = __expf(p + gb2s);
    if (v) { num += g * xv; den += g; }
    __syncthreads();
  }
  snum[wv][lane] = num;
  if (lane == 0) sden[wv] = den;
  __syncthreads();
  if (t < 64) {
    float s = 0.f;
    for (int k = 0; k < 8; ++k) s += snum[k][t];
    pnum[blockIdx.x * 64 + t] = s;
  }
  if (t == 0) {
    float s = 0.f;
    for (int k = 0; k < 8; ++k) s += sden[k];
    pden[blockIdx.x] = s;
  }
}

__global__ void k_final(const float* __restrict__ pnum, const float* __restrict__ pden,
                        float* __restrict__ out) {
  int t = threadIdx.x;  // 64 threads
  float s = 0.f, dn = 0.f;
  for (int b = 0; b < 256; ++b) { s += pnum[b * 64 + t]; dn += pden[b]; }
  out[t] = s / dn;
}

extern "C" void kernel_launch(void* const* d_in, const int* in_sizes, int n_in,
                              void* d_out, int out_size, void* d_ws, size_t ws_size,
                              hipStream_t stream) {
  const int*   nidx = (const int*)d_in[0];
  const int*   ei   = (const int*)d_in[1];
  const float* emb  = (const float*)d_in[2];
  const float* W1   = (const float*)d_in[3];
  const float* as1v = (const float*)d_in[4];
  const float* ad1v = (const float*)d_in[5];
  const float* b1   = (const float*)d_in[6];
  const float* W2   = (const float*)d_in[7];
  const float* as2v = (const float*)d_in[8];
  const float* ad2v = (const float*)d_in[9];
  const float* b2   = (const float*)d_in[10];
  const float* gW1  = (const float*)d_in[11];
  const float* gb1  = (const float*)d_in[12];
  const float* gW2  = (const float*)d_in[13];
  const float* gb2  = (const float*)d_in[14];
  float* out = (float*)d_out;

  const int nN = in_sizes[0];
  const int nE = in_sizes[1] / 2;
  const int eT = nE + nN;

  float* f = (float*)d_ws;
  size_t off = 0;
  float* h1   = f + off; off += (size_t)nN * 256;  // later reused: h2 at h1, x3 at h1+nN*128
  float* x2   = f + off; off += (size_t)nN * 256;
  float* as1  = f + off; off += (size_t)nN * 4;
  float* ad1  = f + off; off += (size_t)nN * 4;
  float* as2  = f + off; off += nN;
  float* ad2  = f + off; off += nN;
  float* pnum = f + off; off += 256 * 64;
  float* pden = f + off; off += 256;
  int* deg    = (int*)(f + off); off += nN;
  int* rowptr = (int*)(f + off); off += nN + 1;
  int* cursor = (int*)(f + off); off += nN;
  int* srt    = (int*)(f + off); off += eT;

  float* h2 = h1;                        // h1 dead after k_agg1
  float* x3 = h1 + (size_t)nN * 128;     // disjoint from h2 (nN*64)

  hipMemsetAsync(deg, 0, (size_t)nN * sizeof(int), stream);

  int eb = (eT + 255) / 256;
  k_deg    <<<eb, 256, 0, stream>>>(ei, deg, nE, eT);
  k_scan   <<<1, 1024, 0, stream>>>(deg, rowptr, cursor, nN, eT);
  k_scatter<<<eb, 256, 0, stream>>>(ei, cursor, srt, nE, eT);

  k_gemm1 <<<(nN + 31) / 32, 512, 0, stream>>>(nidx, emb, W1, as1v, ad1v, h1, as1, ad1, nN);
  k_agg1  <<<(nN + 3) / 4, 256, 0, stream>>>(h1, as1, ad1, b1, rowptr, srt, x2, nN);

  k_gemm2 <<<(nN + 31) / 32, 512, 0, stream>>>(x2, W2, as2v, ad2v, h2, as2, ad2, nN);
  k_agg2  <<<(nN + 3) / 4, 256, 0, stream>>>(h2, as2, ad2, b2, rowptr, srt, x3, nN);

  k_gatepool<<<256, 512, 0, stream>>>(x3, gW1, gb1, gW2, gb2, pnum, pden, nN);
  k_final   <<<1, 64, 0, stream>>>(pnum, pden, out);
}

// Round 3
// 291.940 us; speedup vs baseline: 1.4079x; 1.1511x over previous
//
#include <hip/hip_runtime.h>

typedef float v4 __attribute__((ext_vector_type(4)));

__device__ __forceinline__ float leaky(float x) { return x >= 0.f ? x : 0.2f * x; }
__device__ __forceinline__ float elu(float x) { return x > 0.f ? x : expm1f(x); }

// ---------------- CSR build (dst-major) ----------------
__global__ void k_deg(const int* __restrict__ ei, int* __restrict__ deg, int nE, int eT) {
  int e = blockIdx.x * blockDim.x + threadIdx.x;
  if (e >= eT) return;
  int d = (e < nE) ? ei[nE + e] : (e - nE);   // self-loops appended after real edges
  atomicAdd(&deg[d], 1);
}

__global__ void k_scan(const int* __restrict__ deg, int* __restrict__ rowptr,
                       int* __restrict__ cursor, int nN, int eT) {
  __shared__ int sd[1024];
  int t = threadIdx.x;
  int chunk = (nN + 1023) >> 10;
  int beg = t * chunk;
  int end = beg + chunk; if (end > nN) end = nN;
  int s = 0;
  for (int i = beg; i < end; ++i) s += deg[i];
  sd[t] = s;
  __syncthreads();
  for (int off = 1; off < 1024; off <<= 1) {
    int v = (t >= off) ? sd[t - off] : 0;
    __syncthreads();
    sd[t] += v;
    __syncthreads();
  }
  int run = sd[t] - s;  // exclusive prefix of this thread's chunk
  for (int i = beg; i < end; ++i) { rowptr[i] = run; cursor[i] = run; run += deg[i]; }
  if (t == 0) rowptr[nN] = eT;
}

__global__ void k_scatter(const int* __restrict__ ei, int* __restrict__ cursor,
                          int* __restrict__ srt, int nE, int eT) {
  int e = blockIdx.x * blockDim.x + threadIdx.x;
  if (e >= eT) return;
  int s, d;
  if (e < nE) { s = ei[e]; d = ei[nE + e]; } else { s = d = e - nE; }
  int pos = atomicAdd(&cursor[d], 1);
  srt[pos] = s;
}

// ---- GEMM1: h1[n,256] = emb[nidx[n],128] @ W1[128,256]; epilogue computes as1/ad1 ----
// grid: (node-tiles of 64) x (4 head-tiles of 64 cols); block 256 thr; thread tile 4n x 4c.
__global__ __launch_bounds__(256) void k_gemm1(
    const int* __restrict__ nidx, const float* __restrict__ emb,
    const float* __restrict__ W1, const float* __restrict__ asv,
    const float* __restrict__ adv, float* __restrict__ h1,
    float* __restrict__ as1, float* __restrict__ ad1, int nN) {
  __shared__ __align__(16) float xs[64 * 68];  // [n][k], stride 68: aligned, bank-spread
  __shared__ __align__(16) float Ws[64 * 64];  // [k][c] row-major
  int t = threadIdx.x;
  int nbase = (blockIdx.x >> 2) * 64;
  int head  = blockIdx.x & 3;
  int cbase = head * 64;
  int c0 = (t & 15) * 4;
  int n0 = (t >> 4) * 4;
  float acc[4][4];
  for (int i = 0; i < 4; ++i) for (int j = 0; j < 4; ++j) acc[i][j] = 0.f;
  v4 z = (v4)(0.f);
  for (int kc = 0; kc < 2; ++kc) {
    __syncthreads();
    {  // stage x: thread -> node t>>2, 16 k-floats
      int sn = t >> 2;
      int node = nbase + sn;
      int kp = (t & 3) * 16;
      bool v = node < nN;
      const float* sp = &emb[(size_t)nidx[v ? node : nN - 1] * 128 + kc * 64 + kp];
      v4 a0 = v ? *(const v4*)(sp + 0)  : z;
      v4 a1 = v ? *(const v4*)(sp + 4)  : z;
      v4 a2 = v ? *(const v4*)(sp + 8)  : z;
      v4 a3 = v ? *(const v4*)(sp + 12) : z;
      *(v4*)&xs[sn * 68 + kp + 0]  = a0;
      *(v4*)&xs[sn * 68 + kp + 4]  = a1;
      *(v4*)&xs[sn * 68 + kp + 8]  = a2;
      *(v4*)&xs[sn * 68 + kp + 12] = a3;
    }
    {  // stage W: thread -> k-row t>>2, 16 c-floats
      int kk = t >> 2;
      int cp = (t & 3) * 16;
      const float* wp = &W1[(size_t)(kc * 64 + kk) * 256 + cbase + cp];
      v4 w0 = *(const v4*)(wp + 0);
      v4 w1 = *(const v4*)(wp + 4);
      v4 w2 = *(const v4*)(wp + 8);
      v4 w3 = *(const v4*)(wp + 12);
      *(v4*)&Ws[kk * 64 + cp + 0]  = w0;
      *(v4*)&Ws[kk * 64 + cp + 4]  = w1;
      *(v4*)&Ws[kk * 64 + cp + 8]  = w2;
      *(v4*)&Ws[kk * 64 + cp + 12] = w3;
    }
    __syncthreads();
    #pragma unroll 4
    for (int kk = 0; kk < 64; kk += 4) {
      v4 xv[4], wv[4];
      for (int i = 0; i < 4; ++i) xv[i] = *(const v4*)&xs[(n0 + i) * 68 + kk];
      for (int j = 0; j < 4; ++j) wv[j] = *(const v4*)&Ws[(kk + j) * 64 + c0];
      for (int i = 0; i < 4; ++i)
        for (int j = 0; j < 4; ++j) {
          float xd = xv[i][j];
          acc[i][0] += xd * wv[j][0];
          acc[i][1] += xd * wv[j][1];
          acc[i][2] += xd * wv[j][2];
          acc[i][3] += xd * wv[j][3];
        }
    }
  }
  v4 asl = *(const v4*)&asv[cbase + c0];
  v4 adl = *(const v4*)&adv[cbase + c0];
  for (int i = 0; i < 4; ++i) {
    int node = nbase + n0 + i;
    v4 o; o[0] = acc[i][0]; o[1] = acc[i][1]; o[2] = acc[i][2]; o[3] = acc[i][3];
    float ps = o[0]*asl[0] + o[1]*asl[1] + o[2]*asl[2] + o[3]*asl[3];
    float pd = o[0]*adl[0] + o[1]*adl[1] + o[2]*adl[2] + o[3]*adl[3];
    ps += __shfl_xor(ps, 1); pd += __shfl_xor(pd, 1);
    ps += __shfl_xor(ps, 2); pd += __shfl_xor(pd, 2);
    ps += __shfl_xor(ps, 4); pd += __shfl_xor(pd, 4);
    ps += __shfl_xor(ps, 8); pd += __shfl_xor(pd, 8);
    if (node < nN) {
      *(v4*)&h1[(size_t)node * 256 + cbase + c0] = o;
      if ((t & 15) == 0) {
        as1[(size_t)node * 4 + head] = ps;
        ad1[(size_t)node * 4 + head] = pd;
      }
    }
  }
}

// ---- layer-1 softmax + aggregate + bias + ELU: one wave per node, v4 channels ----
__global__ __launch_bounds__(256) void k_agg1(
    const float* __restrict__ h1, const float* __restrict__ as1,
    const float* __restrict__ ad1, const float* __restrict__ b1,
    const int* __restrict__ rowptr, const int* __restrict__ srt,
    float* __restrict__ x2, int nN) {
  __shared__ int   ss[4][64];
  __shared__ float sw[4][256];
  __shared__ int   mx;
  int t = threadIdx.x;
  int wv = t >> 6, lane = t & 63;
  int n = blockIdx.x * 4 + wv;
  bool valid = n < nN;
  int ms0 = 0, ms1 = 0;
  v4 adn = (v4)(0.f);
  if (valid) {
    ms0 = rowptr[n]; ms1 = rowptr[n + 1];
    adn = *(const v4*)&ad1[(size_t)n * 4];
  }
  if (t == 0) mx = 0;
  __syncthreads();
  int myc = valid ? (ms1 - ms0 + 63) >> 6 : 0;
  if (lane == 0) atomicMax(&mx, myc);
  __syncthreads();
  int nchunk = mx;
  int h = lane >> 4;
  v4 acc = (v4)(0.f);
  float den = 0.f;
  for (int c = 0; c < nchunk; ++c) {
    int base = ms0 + c * 64;
    int m = ms1 - base; if (m > 64) m = 64;
    if (lane < m) {
      int s = srt[base + lane];
      ss[wv][lane] = s;
      v4 a = *(const v4*)&as1[(size_t)s * 4];
      sw[wv][lane * 4 + 0] = __expf(leaky(a[0] + adn[0]));
      sw[wv][lane * 4 + 1] = __expf(leaky(a[1] + adn[1]));
      sw[wv][lane * 4 + 2] = __expf(leaky(a[2] + adn[2]));
      sw[wv][lane * 4 + 3] = __expf(leaky(a[3] + adn[3]));
    }
    __syncthreads();
    #pragma unroll 4
    for (int j = 0; j < m; ++j) {
      int s = ss[wv][j];
      float wj = sw[wv][j * 4 + h];
      v4 hv = *(const v4*)&h1[(size_t)s * 256 + lane * 4];
      acc[0] += wj * hv[0];
      acc[1] += wj * hv[1];
      acc[2] += wj * hv[2];
      acc[3] += wj * hv[3];
      den += wj;
    }
    __syncthreads();
  }
  if (valid) {
    v4 bb = *(const v4*)&b1[lane * 4];
    float inv = 1.f / den;
    v4 o;
    o[0] = elu(acc[0] * inv + bb[0]);
    o[1] = elu(acc[1] * inv + bb[1]);
    o[2] = elu(acc[2] * inv + bb[2]);
    o[3] = elu(acc[3] * inv + bb[3]);
    *(v4*)&x2[(size_t)n * 256 + lane * 4] = o;
  }
}

// ---- GEMM2: h2[n,64] = x2[n,256] @ W2[256,64]; epilogue computes as2/ad2 ----
// grid: node-tiles of 32; block 256 thr; thread tile 2n x 4c; K staged in 4 chunks of 64.
__global__ __launch_bounds__(256) void k_gemm2(
    const float* __restrict__ x2, const float* __restrict__ W2,
    const float* __restrict__ asv, const float* __restrict__ adv,
    float* __restrict__ h2, float* __restrict__ as2, float* __restrict__ ad2, int nN) {
  __shared__ __align__(16) float xs[32 * 68];  // [n][k], stride 68
  __shared__ __align__(16) float Ws[64 * 64];  // [k][c] row-major
  int t = threadIdx.x;
  int nbase = blockIdx.x * 32;
  int c0 = (t & 15) * 4;
  int n0 = (t >> 4) * 2;
  float acc[2][4];
  for (int i = 0; i < 2; ++i) for (int j = 0; j < 4; ++j) acc[i][j] = 0.f;
  v4 z = (v4)(0.f);
  for (int kc = 0; kc < 4; ++kc) {
    __syncthreads();
    {  // stage x: thread -> node t>>3, 8 k-floats
      int sn = t >> 3;
      int node = nbase + sn;
      int kp = (t & 7) * 8;
      bool v = node < nN;
      const float* sp = &x2[(size_t)(v ? node : nN - 1) * 256 + kc * 64 + kp];
      v4 a0 = v ? *(const v4*)(sp + 0) : z;
      v4 a1 = v ? *(const v4*)(sp + 4) : z;
      *(v4*)&xs[sn * 68 + kp + 0] = a0;
      *(v4*)&xs[sn * 68 + kp + 4] = a1;
    }
    {  // stage W: thread -> k-row t>>2, 16 c-floats
      int kk = t >> 2;
      int cp = (t & 3) * 16;
      const float* wp = &W2[(size_t)(kc * 64 + kk) * 64 + cp];
      v4 w0 = *(const v4*)(wp + 0);
      v4 w1 = *(const v4*)(wp + 4);
      v4 w2 = *(const v4*)(wp + 8);
      v4 w3 = *(const v4*)(wp + 12);
      *(v4*)&Ws[kk * 64 + cp + 0]  = w0;
      *(v4*)&Ws[kk * 64 + cp + 4]  = w1;
      *(v4*)&Ws[kk * 64 + cp + 8]  = w2;
      *(v4*)&Ws[kk * 64 + cp + 12] = w3;
    }
    __syncthreads();
    #pragma unroll 4
    for (int kk = 0; kk < 64; kk += 4) {
      v4 xv[2], wv[4];
      for (int i = 0; i < 2; ++i) xv[i] = *(const v4*)&xs[(n0 + i) * 68 + kk];
      for (int j = 0; j < 4; ++j) wv[j] = *(const v4*)&Ws[(kk + j) * 64 + c0];
      for (int i = 0; i < 2; ++i)
        for (int j = 0; j < 4; ++j) {
          float xd = xv[i][j];
          acc[i][0] += xd * wv[j][0];
          acc[i][1] += xd * wv[j][1];
          acc[i][2] += xd * wv[j][2];
          acc[i][3] += xd * wv[j][3];
        }
    }
  }
  v4 asl = *(const v4*)&asv[c0];
  v4 adl = *(const v4*)&adv[c0];
  for (int i = 0; i < 2; ++i) {
    int node = nbase + n0 + i;
    v4 o; o[0] = acc[i][0]; o[1] = acc[i][1]; o[2] = acc[i][2]; o[3] = acc[i][3];
    float ps = o[0]*asl[0] + o[1]*asl[1] + o[2]*asl[2] + o[3]*asl[3];
    float pd = o[0]*adl[0] + o[1]*adl[1] + o[2]*adl[2] + o[3]*adl[3];
    ps += __shfl_xor(ps, 1); pd += __shfl_xor(pd, 1);
    ps += __shfl_xor(ps, 2); pd += __shfl_xor(pd, 2);
    ps += __shfl_xor(ps, 4); pd += __shfl_xor(pd, 4);
    ps += __shfl_xor(ps, 8); pd += __shfl_xor(pd, 8);
    if (node < nN) {
      *(v4*)&h2[(size_t)node * 64 + c0] = o;
      if ((t & 15) == 0) { as2[node] = ps; ad2[node] = pd; }
    }
  }
}

// ---- layer-2 softmax + aggregate + bias + ELU: one wave per node ----
__global__ __launch_bounds__(256) void k_agg2(
    const float* __restrict__ h2, const float* __restrict__ as2,
    const float* __restrict__ ad2, const float* __restrict__ b2,
    const int* __restrict__ rowptr, const int* __restrict__ srt,
    float* __restrict__ x3, int nN) {
  __shared__ int   ss[4][64];
  __shared__ float sw[4][64];
  __shared__ int   mx;
  int t = threadIdx.x;
  int wv = t >> 6, lane = t & 63;
  int n = blockIdx.x * 4 + wv;
  bool valid = n < nN;
  int ms0 = 0, ms1 = 0;
  float adn = 0.f;
  if (valid) { ms0 = rowptr[n]; ms1 = rowptr[n + 1]; adn = ad2[n]; }
  if (t == 0) mx = 0;
  __syncthreads();
  int myc = valid ? (ms1 - ms0 + 63) >> 6 : 0;
  if (lane == 0) atomicMax(&mx, myc);
  __syncthreads();
  int nchunk = mx;
  float acc = 0.f, den = 0.f;
  for (int c = 0; c < nchunk; ++c) {
    int base = ms0 + c * 64;
    int m = ms1 - base; if (m > 64) m = 64;
    if (lane < m) {
      int s = srt[base + lane];
      ss[wv][lane] = s;
      sw[wv][lane] = __expf(leaky(as2[s] + adn));
    }
    __syncthreads();
    #pragma unroll 4
    for (int j = 0; j < m; ++j) {
      int s = ss[wv][j];
      float wj = sw[wv][j];
      acc += wj * h2[(size_t)s * 64 + lane];
      den += wj;
    }
    __syncthreads();
  }
  if (valid) x3[(size_t)n * 64 + lane] = elu(acc / den + b2[lane]);
}

// ---- fused gate MLP + pooling partials (exactly 256 blocks x 512 threads) ----
__global__ __launch_bounds__(512) void k_gatepool(
    const float* __restrict__ x3, const float* __restrict__ gW1,
    const float* __restrict__ gb1, const float* __restrict__ gW2,
    const float* __restrict__ gb2, float* __restrict__ pnum,
    float* __restrict__ pden, int nN) {
  __shared__ __align__(16) float gwT[64 * 68];   // gW1^T, padded (4-float aligned)
  __shared__ float xr[8][64];
  __shared__ float snum[8][64];
  __shared__ float sden[8];
  int t = threadIdx.x;
  int wv = t >> 6, lane = t & 63;
  for (int i = t; i < 4096; i += 512) {
    int d = i >> 6, c = i & 63;
    gwT[c * 68 + d] = gW1[i];
  }
  float gb1l = gb1[lane];
  float gw2l = gW2[lane];
  float gb2s = gb2[0];
  __syncthreads();
  float num = 0.f, den = 0.f;
  int nIt = (nN + 2047) >> 11;
  int off0 = blockIdx.x * 8 + wv;
  for (int it = 0; it < nIt; ++it) {
    int n = off0 + it * 2048;
    bool v = n < nN;
    float xv = v ? x3[(size_t)n * 64 + lane] : 0.f;
    xr[wv][lane] = xv;
    __syncthreads();
    float hid = gb1l;
    for (int d4 = 0; d4 < 64; d4 += 4) {
      v4 xs4 = *(const v4*)&xr[wv][d4];
      v4 gv  = *(const v4*)&gwT[lane * 68 + d4];
      hid += xs4[0] * gv[0] + xs4[1] * gv[1] + xs4[2] * gv[2] + xs4[3] * gv[3];
    }
    hid = fmaxf(hid, 0.f);
    float p = hid * gw2l;
    for (int o = 32; o; o >>= 1) p += __shfl_xor(p, o);
    float g = __expf(p + gb2s);
    if (v) { num += g * xv; den += g; }
    __syncthreads();
  }
  snum[wv][lane] = num;
  if (lane == 0) sden[wv] = den;
  __syncthreads();
  if (t < 64) {
    float s = 0.f;
    for (int k = 0; k < 8; ++k) s += snum[k][t];
    pnum[blockIdx.x * 64 + t] = s;
  }
  if (t == 0) {
    float s = 0.f;
    for (int k = 0; k < 8; ++k) s += sden[k];
    pden[blockIdx.x] = s;
  }
}

__global__ void k_final(const float* __restrict__ pnum, const float* __restrict__ pden,
                        float* __restrict__ out) {
  int t = threadIdx.x;  // 64 threads
  float s = 0.f, dn = 0.f;
  for (int b = 0; b < 256; ++b) { s += pnum[b * 64 + t]; dn += pden[b]; }
  out[t] = s / dn;
}

extern "C" void kernel_launch(void* const* d_in, const int* in_sizes, int n_in,
                              void* d_out, int out_size, void* d_ws, size_t ws_size,
                              hipStream_t stream) {
  const int*   nidx = (const int*)d_in[0];
  const int*   ei   = (const int*)d_in[1];
  const float* emb  = (const float*)d_in[2];
  const float* W1   = (const float*)d_in[3];
  const float* as1v = (const float*)d_in[4];
  const float* ad1v = (const float*)d_in[5];
  const float* b1   = (const float*)d_in[6];
  const float* W2   = (const float*)d_in[7];
  const float* as2v = (const float*)d_in[8];
  const float* ad2v = (const float*)d_in[9];
  const float* b2   = (const float*)d_in[10];
  const float* gW1  = (const float*)d_in[11];
  const float* gb1  = (const float*)d_in[12];
  const float* gW2  = (const float*)d_in[13];
  const float* gb2  = (const float*)d_in[14];
  float* out = (float*)d_out;

  const int nN = in_sizes[0];
  const int nE = in_sizes[1] / 2;
  const int eT = nE + nN;

  float* f = (float*)d_ws;
  size_t off = 0;
  float* h1   = f + off; off += (size_t)nN * 256;  // later reused: h2 at h1, x3 at h1+nN*128
  float* x2   = f + off; off += (size_t)nN * 256;
  float* as1  = f + off; off += (size_t)nN * 4;
  float* ad1  = f + off; off += (size_t)nN * 4;
  float* as2  = f + off; off += nN;
  float* ad2  = f + off; off += nN;
  float* pnum = f + off; off += 256 * 64;
  float* pden = f + off; off += 256;
  int* deg    = (int*)(f + off); off += nN;
  int* rowptr = (int*)(f + off); off += nN + 1;
  int* cursor = (int*)(f + off); off += nN;
  int* srt    = (int*)(f + off); off += eT;

  float* h2 = h1;                        // h1 dead after k_agg1
  float* x3 = h1 + (size_t)nN * 128;     // disjoint from h2 (nN*64)

  hipMemsetAsync(deg, 0, (size_t)nN * sizeof(int), stream);

  int eb = (eT + 255) / 256;
  k_deg    <<<eb, 256, 0, stream>>>(ei, deg, nE, eT);
  k_scan   <<<1, 1024, 0, stream>>>(deg, rowptr, cursor, nN, eT);
  k_scatter<<<eb, 256, 0, stream>>>(ei, cursor, srt, nE, eT);

  int nt64 = (nN + 63) / 64;
  k_gemm1 <<<nt64 * 4, 256, 0, stream>>>(nidx, emb, W1, as1v, ad1v, h1, as1, ad1, nN);
  k_agg1  <<<(nN + 3) / 4, 256, 0, stream>>>(h1, as1, ad1, b1, rowptr, srt, x2, nN);

  k_gemm2 <<<(nN + 31) / 32, 256, 0, stream>>>(x2, W2, as2v, ad2v, h2, as2, ad2, nN);
  k_agg2  <<<(nN + 3) / 4, 256, 0, stream>>>(h2, as2, ad2, b2, rowptr, srt, x3, nN);

  k_gatepool<<<256, 512, 0, stream>>>(x3, gW1, gb1, gW2, gb2, pnum, pden, nN);
  k_final   <<<1, 64, 0, stream>>>(pnum, pden, out);
}

// Round 4
// 289.846 us; speedup vs baseline: 1.4180x; 1.0072x over previous
//
#include <hip/hip_runtime.h>

typedef float v4 __attribute__((ext_vector_type(4)));

__device__ __forceinline__ float leaky(float x) { return x >= 0.f ? x : 0.2f * x; }
__device__ __forceinline__ float elu(float x) { return x > 0.f ? x : expm1f(x); }

// ---------------- CSR build (dst-major) ----------------
__global__ void k_deg(const int* __restrict__ ei, int* __restrict__ deg, int nE, int eT) {
  int e = blockIdx.x * blockDim.x + threadIdx.x;
  if (e >= eT) return;
  int d = (e < nE) ? ei[nE + e] : (e - nE);   // self-loops appended after real edges
  atomicAdd(&deg[d], 1);
}

__global__ void k_scan(const int* __restrict__ deg, int* __restrict__ rowptr,
                       int* __restrict__ cursor, int nN, int eT) {
  __shared__ int sd[1024];
  int t = threadIdx.x;
  int chunk = (nN + 1023) >> 10;
  int beg = t * chunk;
  int end = beg + chunk; if (end > nN) end = nN;
  int s = 0;
  for (int i = beg; i < end; ++i) s += deg[i];
  sd[t] = s;
  __syncthreads();
  for (int off = 1; off < 1024; off <<= 1) {
    int v = (t >= off) ? sd[t - off] : 0;
    __syncthreads();
    sd[t] += v;
    __syncthreads();
  }
  int run = sd[t] - s;  // exclusive prefix of this thread's chunk
  for (int i = beg; i < end; ++i) { rowptr[i] = run; cursor[i] = run; run += deg[i]; }
  if (t == 0) rowptr[nN] = eT;
}

__global__ void k_scatter(const int* __restrict__ ei, int* __restrict__ cursor,
                          int* __restrict__ srt, int nE, int eT) {
  int e = blockIdx.x * blockDim.x + threadIdx.x;
  if (e >= eT) return;
  int s, d;
  if (e < nE) { s = ei[e]; d = ei[nE + e]; } else { s = d = e - nE; }
  int pos = atomicAdd(&cursor[d], 1);
  srt[pos] = s;
}

// ---- GEMM1: h1[n,256] = emb[nidx[n],128] @ W1[128,256]; epilogue computes as1/ad1 ----
// grid: (node-tiles of 64) x (4 head-tiles of 64 cols); block 256 thr; thread tile 4n x 4c.
__global__ __launch_bounds__(256) void k_gemm1(
    const int* __restrict__ nidx, const float* __restrict__ emb,
    const float* __restrict__ W1, const float* __restrict__ asv,
    const float* __restrict__ adv, float* __restrict__ h1,
    float* __restrict__ as1, float* __restrict__ ad1, int nN) {
  __shared__ __align__(16) float xs[64 * 68];  // [n][k], stride 68: aligned, bank-spread
  __shared__ __align__(16) float Ws[64 * 64];  // [k][c] row-major
  int t = threadIdx.x;
  int nbase = (blockIdx.x >> 2) * 64;
  int head  = blockIdx.x & 3;
  int cbase = head * 64;
  int c0 = (t & 15) * 4;
  int n0 = (t >> 4) * 4;
  float acc[4][4];
  for (int i = 0; i < 4; ++i) for (int j = 0; j < 4; ++j) acc[i][j] = 0.f;
  v4 z = (v4)(0.f);
  for (int kc = 0; kc < 2; ++kc) {
    __syncthreads();
    {  // stage x: thread -> node t>>2, 16 k-floats
      int sn = t >> 2;
      int node = nbase + sn;
      int kp = (t & 3) * 16;
      bool v = node < nN;
      const float* sp = &emb[(size_t)nidx[v ? node : nN - 1] * 128 + kc * 64 + kp];
      v4 a0 = v ? *(const v4*)(sp + 0)  : z;
      v4 a1 = v ? *(const v4*)(sp + 4)  : z;
      v4 a2 = v ? *(const v4*)(sp + 8)  : z;
      v4 a3 = v ? *(const v4*)(sp + 12) : z;
      *(v4*)&xs[sn * 68 + kp + 0]  = a0;
      *(v4*)&xs[sn * 68 + kp + 4]  = a1;
      *(v4*)&xs[sn * 68 + kp + 8]  = a2;
      *(v4*)&xs[sn * 68 + kp + 12] = a3;
    }
    {  // stage W: thread -> k-row t>>2, 16 c-floats
      int kk = t >> 2;
      int cp = (t & 3) * 16;
      const float* wp = &W1[(size_t)(kc * 64 + kk) * 256 + cbase + cp];
      v4 w0 = *(const v4*)(wp + 0);
      v4 w1 = *(const v4*)(wp + 4);
      v4 w2 = *(const v4*)(wp + 8);
      v4 w3 = *(const v4*)(wp + 12);
      *(v4*)&Ws[kk * 64 + cp + 0]  = w0;
      *(v4*)&Ws[kk * 64 + cp + 4]  = w1;
      *(v4*)&Ws[kk * 64 + cp + 8]  = w2;
      *(v4*)&Ws[kk * 64 + cp + 12] = w3;
    }
    __syncthreads();
    #pragma unroll 4
    for (int kk = 0; kk < 64; kk += 4) {
      v4 xv[4], wv[4];
      for (int i = 0; i < 4; ++i) xv[i] = *(const v4*)&xs[(n0 + i) * 68 + kk];
      for (int j = 0; j < 4; ++j) wv[j] = *(const v4*)&Ws[(kk + j) * 64 + c0];
      for (int i = 0; i < 4; ++i)
        for (int j = 0; j < 4; ++j) {
          float xd = xv[i][j];
          acc[i][0] += xd * wv[j][0];
          acc[i][1] += xd * wv[j][1];
          acc[i][2] += xd * wv[j][2];
          acc[i][3] += xd * wv[j][3];
        }
    }
  }
  v4 asl = *(const v4*)&asv[cbase + c0];
  v4 adl = *(const v4*)&adv[cbase + c0];
  for (int i = 0; i < 4; ++i) {
    int node = nbase + n0 + i;
    v4 o; o[0] = acc[i][0]; o[1] = acc[i][1]; o[2] = acc[i][2]; o[3] = acc[i][3];
    float ps = o[0]*asl[0] + o[1]*asl[1] + o[2]*asl[2] + o[3]*asl[3];
    float pd = o[0]*adl[0] + o[1]*adl[1] + o[2]*adl[2] + o[3]*adl[3];
    ps += __shfl_xor(ps, 1); pd += __shfl_xor(pd, 1);
    ps += __shfl_xor(ps, 2); pd += __shfl_xor(pd, 2);
    ps += __shfl_xor(ps, 4); pd += __shfl_xor(pd, 4);
    ps += __shfl_xor(ps, 8); pd += __shfl_xor(pd, 8);
    if (node < nN) {
      *(v4*)&h1[(size_t)node * 256 + cbase + c0] = o;
      if ((t & 15) == 0) {
        as1[(size_t)node * 4 + head] = ps;
        ad1[(size_t)node * 4 + head] = pd;
      }
    }
  }
}

// ---- layer-1 softmax + aggregate + bias + ELU ----
// One wave per node, fully decoupled: wave-private LDS scratch, NO block barriers.
__global__ __launch_bounds__(256) void k_agg1(
    const float* __restrict__ h1, const float* __restrict__ as1,
    const float* __restrict__ ad1, const float* __restrict__ b1,
    const int* __restrict__ rowptr, const int* __restrict__ srt,
    float* __restrict__ x2, int nN) {
  __shared__ int   ss[4][64];
  __shared__ float sw[4][256];
  int t = threadIdx.x;
  int wv = t >> 6, lane = t & 63;
  int n = blockIdx.x * 4 + wv;
  if (n >= nN) return;                     // whole wave exits; no barriers in kernel
  int ms0 = rowptr[n], ms1 = rowptr[n + 1];
  v4 adn = *(const v4*)&ad1[(size_t)n * 4];
  int h = lane >> 4;
  v4 acc = (v4)(0.f);
  float den = 0.f;
  for (int base = ms0; base < ms1; base += 64) {
    int m = ms1 - base; if (m > 64) m = 64;
    // drain our own pending LDS reads before overwriting scratch (no-op first iter)
    asm volatile("s_waitcnt lgkmcnt(0)" ::: "memory");
    __builtin_amdgcn_wave_barrier();
    if (lane < m) {
      int s = srt[base + lane];
      ss[wv][lane] = s;
      v4 a = *(const v4*)&as1[(size_t)s * 4];
      sw[wv][lane * 4 + 0] = __expf(leaky(a[0] + adn[0]));
      sw[wv][lane * 4 + 1] = __expf(leaky(a[1] + adn[1]));
      sw[wv][lane * 4 + 2] = __expf(leaky(a[2] + adn[2]));
      sw[wv][lane * 4 + 3] = __expf(leaky(a[3] + adn[3]));
    }
    // make staging writes visible to all lanes of this wave (lockstep => sufficient)
    asm volatile("s_waitcnt lgkmcnt(0)" ::: "memory");
    __builtin_amdgcn_wave_barrier();
    #pragma unroll 8
    for (int j = 0; j < m; ++j) {
      int s = ss[wv][j];
      float wj = sw[wv][j * 4 + h];
      v4 hv = *(const v4*)&h1[(size_t)s * 256 + lane * 4];
      acc[0] += wj * hv[0];
      acc[1] += wj * hv[1];
      acc[2] += wj * hv[2];
      acc[3] += wj * hv[3];
      den += wj;
    }
  }
  v4 bb = *(const v4*)&b1[lane * 4];
  float inv = 1.f / den;
  v4 o;
  o[0] = elu(acc[0] * inv + bb[0]);
  o[1] = elu(acc[1] * inv + bb[1]);
  o[2] = elu(acc[2] * inv + bb[2]);
  o[3] = elu(acc[3] * inv + bb[3]);
  *(v4*)&x2[(size_t)n * 256 + lane * 4] = o;
}

// ---- GEMM2: h2[n,64] = x2[n,256] @ W2[256,64]; epilogue computes as2/ad2 ----
// grid: node-tiles of 32; block 256 thr; thread tile 2n x 4c; K staged in 4 chunks of 64.
__global__ __launch_bounds__(256) void k_gemm2(
    const float* __restrict__ x2, const float* __restrict__ W2,
    const float* __restrict__ asv, const float* __restrict__ adv,
    float* __restrict__ h2, float* __restrict__ as2, float* __restrict__ ad2, int nN) {
  __shared__ __align__(16) float xs[32 * 68];  // [n][k], stride 68
  __shared__ __align__(16) float Ws[64 * 64];  // [k][c] row-major
  int t = threadIdx.x;
  int nbase = blockIdx.x * 32;
  int c0 = (t & 15) * 4;
  int n0 = (t >> 4) * 2;
  float acc[2][4];
  for (int i = 0; i < 2; ++i) for (int j = 0; j < 4; ++j) acc[i][j] = 0.f;
  v4 z = (v4)(0.f);
  for (int kc = 0; kc < 4; ++kc) {
    __syncthreads();
    {  // stage x: thread -> node t>>3, 8 k-floats
      int sn = t >> 3;
      int node = nbase + sn;
      int kp = (t & 7) * 8;
      bool v = node < nN;
      const float* sp = &x2[(size_t)(v ? node : nN - 1) * 256 + kc * 64 + kp];
      v4 a0 = v ? *(const v4*)(sp + 0) : z;
      v4 a1 = v ? *(const v4*)(sp + 4) : z;
      *(v4*)&xs[sn * 68 + kp + 0] = a0;
      *(v4*)&xs[sn * 68 + kp + 4] = a1;
    }
    {  // stage W: thread -> k-row t>>2, 16 c-floats
      int kk = t >> 2;
      int cp = (t & 3) * 16;
      const float* wp = &W2[(size_t)(kc * 64 + kk) * 64 + cp];
      v4 w0 = *(const v4*)(wp + 0);
      v4 w1 = *(const v4*)(wp + 4);
      v4 w2 = *(const v4*)(wp + 8);
      v4 w3 = *(const v4*)(wp + 12);
      *(v4*)&Ws[kk * 64 + cp + 0]  = w0;
      *(v4*)&Ws[kk * 64 + cp + 4]  = w1;
      *(v4*)&Ws[kk * 64 + cp + 8]  = w2;
      *(v4*)&Ws[kk * 64 + cp + 12] = w3;
    }
    __syncthreads();
    #pragma unroll 4
    for (int kk = 0; kk < 64; kk += 4) {
      v4 xv[2], wv[4];
      for (int i = 0; i < 2; ++i) xv[i] = *(const v4*)&xs[(n0 + i) * 68 + kk];
      for (int j = 0; j < 4; ++j) wv[j] = *(const v4*)&Ws[(kk + j) * 64 + c0];
      for (int i = 0; i < 2; ++i)
        for (int j = 0; j < 4; ++j) {
          float xd = xv[i][j];
          acc[i][0] += xd * wv[j][0];
          acc[i][1] += xd * wv[j][1];
          acc[i][2] += xd * wv[j][2];
          acc[i][3] += xd * wv[j][3];
        }
    }
  }
  v4 asl = *(const v4*)&asv[c0];
  v4 adl = *(const v4*)&adv[c0];
  for (int i = 0; i < 2; ++i) {
    int node = nbase + n0 + i;
    v4 o; o[0] = acc[i][0]; o[1] = acc[i][1]; o[2] = acc[i][2]; o[3] = acc[i][3];
    float ps = o[0]*asl[0] + o[1]*asl[1] + o[2]*asl[2] + o[3]*asl[3];
    float pd = o[0]*adl[0] + o[1]*adl[1] + o[2]*adl[2] + o[3]*adl[3];
    ps += __shfl_xor(ps, 1); pd += __shfl_xor(pd, 1);
    ps += __shfl_xor(ps, 2); pd += __shfl_xor(pd, 2);
    ps += __shfl_xor(ps, 4); pd += __shfl_xor(pd, 4);
    ps += __shfl_xor(ps, 8); pd += __shfl_xor(pd, 8);
    if (node < nN) {
      *(v4*)&h2[(size_t)node * 64 + c0] = o;
      if ((t & 15) == 0) { as2[node] = ps; ad2[node] = pd; }
    }
  }
}

// ---- layer-2 softmax + aggregate + bias + ELU: one wave per node, barrier-free ----
__global__ __launch_bounds__(256) void k_agg2(
    const float* __restrict__ h2, const float* __restrict__ as2,
    const float* __restrict__ ad2, const float* __restrict__ b2,
    const int* __restrict__ rowptr, const int* __restrict__ srt,
    float* __restrict__ x3, int nN) {
  __shared__ int   ss[4][64];
  __shared__ float sw[4][64];
  int t = threadIdx.x;
  int wv = t >> 6, lane = t & 63;
  int n = blockIdx.x * 4 + wv;
  if (n >= nN) return;                     // whole wave exits; no barriers in kernel
  int ms0 = rowptr[n], ms1 = rowptr[n + 1];
  float adn = ad2[n];
  float acc = 0.f, den = 0.f;
  for (int base = ms0; base < ms1; base += 64) {
    int m = ms1 - base; if (m > 64) m = 64;
    asm volatile("s_waitcnt lgkmcnt(0)" ::: "memory");
    __builtin_amdgcn_wave_barrier();
    if (lane < m) {
      int s = srt[base + lane];
      ss[wv][lane] = s;
      sw[wv][lane] = __expf(leaky(as2[s] + adn));
    }
    asm volatile("s_waitcnt lgkmcnt(0)" ::: "memory");
    __builtin_amdgcn_wave_barrier();
    #pragma unroll 8
    for (int j = 0; j < m; ++j) {
      int s = ss[wv][j];
      float wj = sw[wv][j];
      acc += wj * h2[(size_t)s * 64 + lane];
      den += wj;
    }
  }
  x3[(size_t)n * 64 + lane] = elu(acc / den + b2[lane]);
}

// ---- fused gate MLP + pooling partials (exactly 256 blocks x 512 threads) ----
__global__ __launch_bounds__(512) void k_gatepool(
    const float* __restrict__ x3, const float* __restrict__ gW1,
    const float* __restrict__ gb1, const float* __restrict__ gW2,
    const float* __restrict__ gb2, float* __restrict__ pnum,
    float* __restrict__ pden, int nN) {
  __shared__ __align__(16) float gwT[64 * 68];   // gW1^T, padded (4-float aligned)
  __shared__ float xr[8][64];
  __shared__ float snum[8][64];
  __shared__ float sden[8];
  int t = threadIdx.x;
  int wv = t >> 6, lane = t & 63;
  for (int i = t; i < 4096; i += 512) {
    int d = i >> 6, c = i & 63;
    gwT[c * 68 + d] = gW1[i];
  }
  float gb1l = gb1[lane];
  float gw2l = gW2[lane];
  float gb2s = gb2[0];
  __syncthreads();
  float num = 0.f, den = 0.f;
  int nIt = (nN + 2047) >> 11;
  int off0 = blockIdx.x * 8 + wv;
  for (int it = 0; it < nIt; ++it) {
    int n = off0 + it * 2048;
    bool v = n < nN;
    float xv = v ? x3[(size_t)n * 64 + lane] : 0.f;
    xr[wv][lane] = xv;
    asm volatile("s_waitcnt lgkmcnt(0)" ::: "memory");
    __builtin_amdgcn_wave_barrier();
    float hid = gb1l;
    for (int d4 = 0; d4 < 64; d4 += 4) {
      v4 xs4 = *(const v4*)&xr[wv][d4];
      v4 gv  = *(const v4*)&gwT[lane * 68 + d4];
      hid += xs4[0] * gv[0] + xs4[1] * gv[1] + xs4[2] * gv[2] + xs4[3] * gv[3];
    }
    hid = fmaxf(hid, 0.f);
    float p = hid * gw2l;
    for (int o = 32; o; o >>= 1) p += __shfl_xor(p, o);
    float g = __expf(p + gb2s);
    if (v) { num += g * xv; den += g; }
    asm volatile("s_waitcnt lgkmcnt(0)" ::: "memory");
    __builtin_amdgcn_wave_barrier();
  }
  snum[wv][lane] = num;
  if (lane == 0) sden[wv] = den;
  __syncthreads();
  if (t < 64) {
    float s = 0.f;
    for (int k = 0; k < 8; ++k) s += snum[k][t];
    pnum[blockIdx.x * 64 + t] = s;
  }
  if (t == 0) {
    float s = 0.f;
    for (int k = 0; k < 8; ++k) s += sden[k];
    pden[blockIdx.x] = s;
  }
}

__global__ void k_final(const float* __restrict__ pnum, const float* __restrict__ pden,
                        float* __restrict__ out) {
  int t = threadIdx.x;  // 64 threads
  float s = 0.f, dn = 0.f;
  for (int b = 0; b < 256; ++b) { s += pnum[b * 64 + t]; dn += pden[b]; }
  out[t] = s / dn;
}

extern "C" void kernel_launch(void* const* d_in, const int* in_sizes, int n_in,
                              void* d_out, int out_size, void* d_ws, size_t ws_size,
                              hipStream_t stream) {
  const int*   nidx = (const int*)d_in[0];
  const int*   ei   = (const int*)d_in[1];
  const float* emb  = (const float*)d_in[2];
  const float* W1   = (const float*)d_in[3];
  const float* as1v = (const float*)d_in[4];
  const float* ad1v = (const float*)d_in[5];
  const float* b1   = (const float*)d_in[6];
  const float* W2   = (const float*)d_in[7];
  const float* as2v = (const float*)d_in[8];
  const float* ad2v = (const float*)d_in[9];
  const float* b2   = (const float*)d_in[10];
  const float* gW1  = (const float*)d_in[11];
  const float* gb1  = (const float*)d_in[12];
  const float* gW2  = (const float*)d_in[13];
  const float* gb2  = (const float*)d_in[14];
  float* out = (float*)d_out;

  const int nN = in_sizes[0];
  const int nE = in_sizes[1] / 2;
  const int eT = nE + nN;

  float* f = (float*)d_ws;
  size_t off = 0;
  float* h1   = f + off; off += (size_t)nN * 256;  // later reused: h2 at h1, x3 at h1+nN*128
  float* x2   = f + off; off += (size_t)nN * 256;
  float* as1  = f + off; off += (size_t)nN * 4;
  float* ad1  = f + off; off += (size_t)nN * 4;
  float* as2  = f + off; off += nN;
  float* ad2  = f + off; off += nN;
  float* pnum = f + off; off += 256 * 64;
  float* pden = f + off; off += 256;
  int* deg    = (int*)(f + off); off += nN;
  int* rowptr = (int*)(f + off); off += nN + 1;
  int* cursor = (int*)(f + off); off += nN;
  int* srt    = (int*)(f + off); off += eT;

  float* h2 = h1;                        // h1 dead after k_agg1
  float* x3 = h1 + (size_t)nN * 128;     // disjoint from h2 (nN*64)

  hipMemsetAsync(deg, 0, (size_t)nN * sizeof(int), stream);

  int eb = (eT + 255) / 256;
  k_deg    <<<eb, 256, 0, stream>>>(ei, deg, nE, eT);
  k_scan   <<<1, 1024, 0, stream>>>(deg, rowptr, cursor, nN, eT);
  k_scatter<<<eb, 256, 0, stream>>>(ei, cursor, srt, nE, eT);

  int nt64 = (nN + 63) / 64;
  k_gemm1 <<<nt64 * 4, 256, 0, stream>>>(nidx, emb, W1, as1v, ad1v, h1, as1, ad1, nN);
  k_agg1  <<<(nN + 3) / 4, 256, 0, stream>>>(h1, as1, ad1, b1, rowptr, srt, x2, nN);

  k_gemm2 <<<(nN + 31) / 32, 256, 0, stream>>>(x2, W2, as2v, ad2v, h2, as2, ad2, nN);
  k_agg2  <<<(nN + 3) / 4, 256, 0, stream>>>(h2, as2, ad2, b2, rowptr, srt, x3, nN);

  k_gatepool<<<256, 512, 0, stream>>>(x3, gW1, gb1, gW2, gb2, pnum, pden, nN);
  k_final   <<<1, 64, 0, stream>>>(pnum, pden, out);
}